// Round 5
// baseline (461.903 us; speedup 1.0000x reference)
//
#include <hip/hip_runtime.h>
#include <hip/hip_bf16.h>
#include <math.h>

typedef short bf16x8 __attribute__((ext_vector_type(8)));
typedef short bf16x4 __attribute__((ext_vector_type(4)));
typedef float f32x4 __attribute__((ext_vector_type(4)));

#define NSEQ 2048
#define DMODEL 2048
#define NH 16
#define HD 128
#define BATCH 2
#define MROWS 4096  // BATCH*NSEQ

__device__ __forceinline__ unsigned short f2b(float f) {
    __hip_bfloat16 h = __float2bfloat16(f);
    return *reinterpret_cast<unsigned short*>(&h);
}
__device__ __forceinline__ float b2f(unsigned short u) {
    __hip_bfloat16 h;
    *reinterpret_cast<unsigned short*>(&h) = u;
    return __bfloat162float(h);
}

__device__ __forceinline__ void gld_lds16(const unsigned short* g, unsigned short* l) {
    __builtin_amdgcn_global_load_lds(
        (const __attribute__((address_space(1))) unsigned int*)(const void*)g,
        (__attribute__((address_space(3))) unsigned int*)(void*)l,
        16, 0, 0);
}

// ---------------- fused cast fp32 -> bf16 for x + 4 weights ----------------
__global__ __launch_bounds__(256) void cast_all_kernel(const float* __restrict__ x,
                                                       const float* __restrict__ wq,
                                                       const float* __restrict__ wk,
                                                       const float* __restrict__ wv,
                                                       const float* __restrict__ wo,
                                                       unsigned short* __restrict__ xb,
                                                       unsigned short* __restrict__ wqb) {
    int bid = blockIdx.x;
    const float* src;
    unsigned short* dst;
    int off;
    if (bid < 4096) {
        src = x; dst = xb; off = bid;
    } else {
        int w = (bid - 4096) >> 11;
        src = (w == 0) ? wq : (w == 1) ? wk : (w == 2) ? wv : wo;
        dst = wqb + (size_t)w * 4194304;
        off = (bid - 4096) & 2047;
    }
    int i = (off * 256 + threadIdx.x) * 8;
    float4 a = *(const float4*)(src + i);
    float4 b = *(const float4*)(src + i + 4);
    union { unsigned short u[8]; uint4 v; } tmp;
    tmp.u[0] = f2b(a.x); tmp.u[1] = f2b(a.y); tmp.u[2] = f2b(a.z); tmp.u[3] = f2b(a.w);
    tmp.u[4] = f2b(b.x); tmp.u[5] = f2b(b.y); tmp.u[6] = f2b(b.z); tmp.u[7] = f2b(b.w);
    *(uint4*)(dst + i) = tmp.v;
}

// ---------------- QKV GEMM: A[4096][2048] x W[6144][2048]^T ----------------
// n in [0,4096): Q/K row-major (two contiguous 16MB buffers). n in [4096,6144): V transposed.
__global__ __launch_bounds__(256) void gemm_qkv(const unsigned short* __restrict__ A,
                                                const unsigned short* __restrict__ Bw,
                                                unsigned short* __restrict__ qk,
                                                unsigned short* __restrict__ vt) {
    __shared__ unsigned short sA[128 * 32];
    __shared__ unsigned short sB[128 * 32];
    const int K = DMODEL;
    const int tid = threadIdx.x;
    const int wave = tid >> 6, lane = tid & 63;
    const int m0 = blockIdx.y * 128, n0 = blockIdx.x * 128;
    const int wm = (wave >> 1) * 64, wn = (wave & 1) * 64;

    f32x4 acc[4][4] = {};

    const int srow = wave * 32 + (lane >> 2);
    const int scol = (lane & 3) * 8;
    const unsigned short* Ag = A + (size_t)(m0 + srow) * K + scol;
    const unsigned short* Bg = Bw + (size_t)(n0 + srow) * K + scol;
    unsigned short* sA0 = &sA[(wave * 32) * 32];
    unsigned short* sA1 = &sA[(wave * 32 + 16) * 32];
    unsigned short* sB0 = &sB[(wave * 32) * 32];
    unsigned short* sB1 = &sB[(wave * 32 + 16) * 32];
    const int fr = lane & 15, fo = (lane >> 4) * 8;

    for (int kb = 0; kb < K; kb += 32) {
        gld_lds16(Ag + kb, sA0);
        gld_lds16(Ag + (size_t)16 * K + kb, sA1);
        gld_lds16(Bg + kb, sB0);
        gld_lds16(Bg + (size_t)16 * K + kb, sB1);
        __syncthreads();
        bf16x8 af[4], bfr[4];
        #pragma unroll
        for (int mt = 0; mt < 4; mt++)
            af[mt] = *(const bf16x8*)&sA[(wm + mt * 16 + fr) * 32 + fo];
        #pragma unroll
        for (int nt = 0; nt < 4; nt++)
            bfr[nt] = *(const bf16x8*)&sB[(wn + nt * 16 + fr) * 32 + fo];
        #pragma unroll
        for (int mt = 0; mt < 4; mt++)
            #pragma unroll
            for (int nt = 0; nt < 4; nt++)
                acc[mt][nt] = __builtin_amdgcn_mfma_f32_16x16x32_bf16(af[mt], bfr[nt], acc[mt][nt], 0, 0, 0);
        __syncthreads();
    }

    const int g4 = (lane >> 4) * 4, c0 = lane & 15;
    if (n0 < 4096) {
        #pragma unroll
        for (int mt = 0; mt < 4; mt++)
            #pragma unroll
            for (int nt = 0; nt < 4; nt++) {
                int col = n0 + wn + nt * 16 + c0;
                size_t base = (size_t)(col >> 11) * 8388608 + (size_t)(col & 2047);
                #pragma unroll
                for (int r = 0; r < 4; r++) {
                    int row = m0 + wm + mt * 16 + g4 + r;
                    qk[base + (size_t)row * 2048] = f2b(acc[mt][nt][r]);
                }
            }
    } else {
        #pragma unroll
        for (int mt = 0; mt < 4; mt++) {
            int mbase = m0 + wm + mt * 16 + g4;
            int bb = mbase >> 11;
            int nn = mbase & 2047;
            #pragma unroll
            for (int nt = 0; nt < 4; nt++) {
                int d = n0 - 4096 + wn + nt * 16 + c0;
                union { unsigned short u[4]; uint2 v; } o;
                #pragma unroll
                for (int r = 0; r < 4; r++) o.u[r] = f2b(acc[mt][nt][r]);
                *(uint2*)(vt + ((size_t)(bb * 2048 + d)) * 2048 + nn) = o.v;
            }
        }
    }
}

// ---------------- plain GEMM (fp32 out) for the output projection ----------------
__global__ __launch_bounds__(256) void gemm_out(const unsigned short* __restrict__ A,
                                                const unsigned short* __restrict__ Bw,
                                                float* __restrict__ Cf) {
    __shared__ unsigned short sA[128 * 32];
    __shared__ unsigned short sB[128 * 32];
    const int K = DMODEL, Nn = DMODEL;
    const int tid = threadIdx.x;
    const int wave = tid >> 6, lane = tid & 63;
    const int m0 = blockIdx.y * 128, n0 = blockIdx.x * 128;
    const int wm = (wave >> 1) * 64, wn = (wave & 1) * 64;

    f32x4 acc[4][4] = {};

    const int srow = wave * 32 + (lane >> 2);
    const int scol = (lane & 3) * 8;
    const unsigned short* Ag = A + (size_t)(m0 + srow) * K + scol;
    const unsigned short* Bg = Bw + (size_t)(n0 + srow) * K + scol;
    unsigned short* sA0 = &sA[(wave * 32) * 32];
    unsigned short* sA1 = &sA[(wave * 32 + 16) * 32];
    unsigned short* sB0 = &sB[(wave * 32) * 32];
    unsigned short* sB1 = &sB[(wave * 32 + 16) * 32];
    const int fr = lane & 15, fo = (lane >> 4) * 8;

    for (int kb = 0; kb < K; kb += 32) {
        gld_lds16(Ag + kb, sA0);
        gld_lds16(Ag + (size_t)16 * K + kb, sA1);
        gld_lds16(Bg + kb, sB0);
        gld_lds16(Bg + (size_t)16 * K + kb, sB1);
        __syncthreads();
        bf16x8 af[4], bfr[4];
        #pragma unroll
        for (int mt = 0; mt < 4; mt++)
            af[mt] = *(const bf16x8*)&sA[(wm + mt * 16 + fr) * 32 + fo];
        #pragma unroll
        for (int nt = 0; nt < 4; nt++)
            bfr[nt] = *(const bf16x8*)&sB[(wn + nt * 16 + fr) * 32 + fo];
        #pragma unroll
        for (int mt = 0; mt < 4; mt++)
            #pragma unroll
            for (int nt = 0; nt < 4; nt++)
                acc[mt][nt] = __builtin_amdgcn_mfma_f32_16x16x32_bf16(af[mt], bfr[nt], acc[mt][nt], 0, 0, 0);
        __syncthreads();
    }

    const int g4 = (lane >> 4) * 4, c0 = lane & 15;
    #pragma unroll
    for (int mt = 0; mt < 4; mt++)
        #pragma unroll
        for (int nt = 0; nt < 4; nt++) {
            int col = n0 + wn + nt * 16 + c0;
            #pragma unroll
            for (int r = 0; r < 4; r++) {
                int row = m0 + wm + mt * 16 + g4 + r;
                Cf[(size_t)row * Nn + col] = acc[mt][nt][r];
            }
        }
}

// ---------------- RoPE, vectorized. Q scale includes log2(e)/sqrt(hd). ----------------
__global__ __launch_bounds__(256) void rope_kernel(unsigned short* __restrict__ Q,
                                                   unsigned short* __restrict__ Kb) {
    int t = blockIdx.x * 256 + threadIdx.x;   // 1,048,576 threads
    int dq = t & 15, h = (t >> 4) & 15, m = t >> 8;
    int n = m & (NSEQ - 1);
    size_t base = (size_t)m * DMODEL + h * HD + dq * 4;

    union U4 { unsigned short u[4]; uint2 v; };
    U4 qlo, qhi, klo, khi, oql, oqh, okl, okh;
    qlo.v = *(const uint2*)(Q + base);
    qhi.v = *(const uint2*)(Q + base + 64);
    klo.v = *(const uint2*)(Kb + base);
    khi.v = *(const uint2*)(Kb + base + 64);

    const float scq = 0.12751677940818388f;   // log2(e)/sqrt(128)
    #pragma unroll
    for (int j = 0; j < 4; j++) {
        int d = dq * 4 + j;
        float invf = exp2f((float)d * -0.2076205059304545f);  // 10000^(-d/64)
        float fr = (float)n * invf;
        float sv, cv;
        __sincosf(fr, &sv, &cv);
        float q1 = b2f(qlo.u[j]), q2 = b2f(qhi.u[j]);
        float k1 = b2f(klo.u[j]), k2 = b2f(khi.u[j]);
        oql.u[j] = f2b((q1 * cv - q2 * sv) * scq);
        oqh.u[j] = f2b((q2 * cv + q1 * sv) * scq);
        okl.u[j] = f2b(k1 * cv - k2 * sv);
        okh.u[j] = f2b(k2 * cv + k1 * sv);
    }
    *(uint2*)(Q + base)       = oql.v;
    *(uint2*)(Q + base + 64)  = oqh.v;
    *(uint2*)(Kb + base)      = okl.v;
    *(uint2*)(Kb + base + 64) = okh.v;
}

// ---------------- Flash attention, S^T formulation (R3 layout: padded strides) ------
// qt on blockIdx.x so consecutive blocks share one (b,h) K/V slice (L2 locality).
// Scores arrive in log2-domain (Q pre-scaled by log2(e)/sqrt(hd)) -> exp2f.
__global__ __launch_bounds__(256) void attn_kernel(const unsigned short* __restrict__ Q,
                                                   const unsigned short* __restrict__ Kg,
                                                   const unsigned short* __restrict__ Vt,
                                                   unsigned short* __restrict__ O) {
    __shared__ unsigned short sK[64 * 136];   // [kv][d], stride 136
    __shared__ unsigned short sV[128 * 88];   // V^T tile [d][kv], stride 88

    const int bh = blockIdx.y;
    const int b = bh >> 4, h = bh & 15;
    const int qt = blockIdx.x;                // 0..15, 128 q-rows each
    const int tid = threadIdx.x, wave = tid >> 6, lane = tid & 63;
    const int c0 = lane & 15, grp = lane >> 4;

    // Q as B-operand fragments: lane holds Q[q = base + c0][d = grp*8+j (+ks*32)]
    bf16x8 qf[2][4];
    {
        const unsigned short* Qbase = Q + (size_t)(b * NSEQ + qt * 128 + wave * 32 + c0) * DMODEL + h * HD + grp * 8;
        #pragma unroll
        for (int nt = 0; nt < 2; nt++)
            #pragma unroll
            for (int ks = 0; ks < 4; ks++)
                qf[nt][ks] = *(const bf16x8*)(Qbase + (size_t)nt * 16 * DMODEL + ks * 32);
    }

    f32x4 oacc[8][2] = {};                    // O^T[d = mo*16+grp*4+r][q = nt*16+c0]
    float lsum[2] = {0.f, 0.f};

    const unsigned short* Kbase = Kg + (size_t)(b * NSEQ) * DMODEL + h * HD;
    const unsigned short* Vbase = Vt + (size_t)(bh * HD) * NSEQ;

    for (int kv0 = 0; kv0 < NSEQ; kv0 += 64) {
        __syncthreads();
        // stage K tile [64][128] -> sK
        #pragma unroll
        for (int i = 0; i < 4; i++) {
            int fl = i * 256 + tid;
            int rr = fl >> 4, cc = fl & 15;
            *(uint4*)&sK[rr * 136 + cc * 8] = *(const uint4*)(Kbase + (size_t)(kv0 + rr) * DMODEL + cc * 8);
        }
        // stage V^T tile [128][64] -> sV
        #pragma unroll
        for (int i = 0; i < 4; i++) {
            int fl = i * 256 + tid;
            int rr = fl >> 3, cc = fl & 7;
            *(uint4*)&sV[rr * 88 + cc * 8] = *(const uint4*)(Vbase + (size_t)rr * NSEQ + kv0 + cc * 8);
        }
        __syncthreads();

        // S^T[kv][q]: A = K rows (m=kv), B = Q rows (n=q)
        f32x4 s[4][2] = {};
        #pragma unroll
        for (int ks = 0; ks < 4; ks++) {
            bf16x8 kf[4];
            #pragma unroll
            for (int mt = 0; mt < 4; mt++)
                kf[mt] = *(const bf16x8*)&sK[(mt * 16 + c0) * 136 + ks * 32 + grp * 8];
            #pragma unroll
            for (int mt = 0; mt < 4; mt++)
                #pragma unroll
                for (int nt = 0; nt < 2; nt++)
                    s[mt][nt] = __builtin_amdgcn_mfma_f32_16x16x32_bf16(kf[mt], qf[nt][ks], s[mt][nt], 0, 0, 0);
        }

        // exp2 + per-lane row-sum + pack into PV B-fragments (k = grp*4+j)
        bf16x4 pk[4][2];
        #pragma unroll
        for (int mt = 0; mt < 4; mt++)
            #pragma unroll
            for (int nt = 0; nt < 2; nt++) {
                float p0 = exp2f(s[mt][nt][0]);
                float p1 = exp2f(s[mt][nt][1]);
                float p2 = exp2f(s[mt][nt][2]);
                float p3 = exp2f(s[mt][nt][3]);
                lsum[nt] += (p0 + p1) + (p2 + p3);
                bf16x4 t;
                t[0] = (short)f2b(p0); t[1] = (short)f2b(p1);
                t[2] = (short)f2b(p2); t[3] = (short)f2b(p3);
                pk[mt][nt] = t;
            }

        // O^T += V^T . P^T  via 16x16x16 MFMA; A-frags (b64) from sV, B-frags in regs
        #pragma unroll
        for (int mtK = 0; mtK < 4; mtK++) {
            bf16x4 va[8];
            #pragma unroll
            for (int mo = 0; mo < 8; mo++)
                va[mo] = *(const bf16x4*)&sV[(mo * 16 + c0) * 88 + mtK * 16 + grp * 4];
            #pragma unroll
            for (int mo = 0; mo < 8; mo++)
                #pragma unroll
                for (int nt = 0; nt < 2; nt++)
                    oacc[mo][nt] = __builtin_amdgcn_mfma_f32_16x16x16bf16_1k(va[mo], pk[mtK][nt], oacc[mo][nt], 0, 0, 0);
        }
    }

    // epilogue: cross-grp sum reduce, normalize, store
    float invl[2];
    #pragma unroll
    for (int nt = 0; nt < 2; nt++) {
        float li = lsum[nt];
        li += __shfl_xor(li, 16);
        li += __shfl_xor(li, 32);
        invl[nt] = 1.0f / li;
    }
    #pragma unroll
    for (int mo = 0; mo < 8; mo++)
        #pragma unroll
        for (int nt = 0; nt < 2; nt++) {
            union { unsigned short u[4]; uint2 v; } o;
            #pragma unroll
            for (int r = 0; r < 4; r++)
                o.u[r] = f2b(oacc[mo][nt][r] * invl[nt]);
            int row = b * NSEQ + qt * 128 + wave * 32 + nt * 16 + c0;
            int col = h * HD + mo * 16 + grp * 4;
            *(uint2*)(O + (size_t)row * DMODEL + col) = o.v;
        }
}

extern "C" void kernel_launch(void* const* d_in, const int* in_sizes, int n_in,
                              void* d_out, int out_size, void* d_ws, size_t ws_size,
                              hipStream_t stream) {
    const float* x  = (const float*)d_in[0];
    const float* Wq = (const float*)d_in[1];
    const float* Wk = (const float*)d_in[2];
    const float* Wv = (const float*)d_in[3];
    const float* Wo = (const float*)d_in[4];

    char* ws = (char*)d_ws;
    // xb(16M, reused as attn O) | wqb..wob (4x8M contiguous) | qb(16M)+kb(16M) contiguous | vt(16M)
    unsigned short* xb  = (unsigned short*)(ws);
    unsigned short* wqb = (unsigned short*)(ws + 16777216);
    unsigned short* wob = (unsigned short*)(ws + 16777216 + 3 * 8388608);
    unsigned short* qb  = (unsigned short*)(ws + 50331648);
    unsigned short* kb  = (unsigned short*)(ws + 67108864);
    unsigned short* vt  = (unsigned short*)(ws + 83886080);

    cast_all_kernel<<<12288, 256, 0, stream>>>(x, Wq, Wk, Wv, Wo, xb, wqb);

    gemm_qkv<<<dim3(48, 32), 256, 0, stream>>>(xb, wqb, qb, vt);

    rope_kernel<<<4096, 256, 0, stream>>>(qb, kb);

    attn_kernel<<<dim3(16, 32), 256, 0, stream>>>(qb, kb, vt, xb);

    gemm_out<<<dim3(16, 32), 256, 0, stream>>>(xb, wob, (float*)d_out);
}

// Round 6
// 423.066 us; speedup vs baseline: 1.0918x; 1.0918x over previous
//
#include <hip/hip_runtime.h>
#include <hip/hip_bf16.h>
#include <math.h>

typedef short bf16x8 __attribute__((ext_vector_type(8)));
typedef short bf16x4 __attribute__((ext_vector_type(4)));
typedef float f32x4 __attribute__((ext_vector_type(4)));

#define NSEQ 2048
#define DMODEL 2048
#define NH 16
#define HD 128
#define BATCH 2
#define MROWS 4096  // BATCH*NSEQ

__device__ __forceinline__ unsigned short f2b(float f) {
    __hip_bfloat16 h = __float2bfloat16(f);
    return *reinterpret_cast<unsigned short*>(&h);
}
__device__ __forceinline__ float b2f(unsigned short u) {
    __hip_bfloat16 h;
    *reinterpret_cast<unsigned short*>(&h) = u;
    return __bfloat162float(h);
}

__device__ __forceinline__ void gld_lds16(const unsigned short* g, unsigned short* l) {
    __builtin_amdgcn_global_load_lds(
        (const __attribute__((address_space(1))) unsigned int*)(const void*)g,
        (__attribute__((address_space(3))) unsigned int*)(void*)l,
        16, 0, 0);
}

// ---------------- fused cast fp32 -> bf16 for x + 4 weights ----------------
__global__ __launch_bounds__(256) void cast_all_kernel(const float* __restrict__ x,
                                                       const float* __restrict__ wq,
                                                       const float* __restrict__ wk,
                                                       const float* __restrict__ wv,
                                                       const float* __restrict__ wo,
                                                       unsigned short* __restrict__ xb,
                                                       unsigned short* __restrict__ wqb) {
    int bid = blockIdx.x;
    const float* src;
    unsigned short* dst;
    int off;
    if (bid < 4096) {
        src = x; dst = xb; off = bid;
    } else {
        int w = (bid - 4096) >> 11;
        src = (w == 0) ? wq : (w == 1) ? wk : (w == 2) ? wv : wo;
        dst = wqb + (size_t)w * 4194304;
        off = (bid - 4096) & 2047;
    }
    int i = (off * 256 + threadIdx.x) * 8;
    float4 a = *(const float4*)(src + i);
    float4 b = *(const float4*)(src + i + 4);
    union { unsigned short u[8]; uint4 v; } tmp;
    tmp.u[0] = f2b(a.x); tmp.u[1] = f2b(a.y); tmp.u[2] = f2b(a.z); tmp.u[3] = f2b(a.w);
    tmp.u[4] = f2b(b.x); tmp.u[5] = f2b(b.y); tmp.u[6] = f2b(b.z); tmp.u[7] = f2b(b.w);
    *(uint4*)(dst + i) = tmp.v;
}

// ---------------- QKV GEMM: A[4096][2048] x W[6144][2048]^T ----------------
// n in [0,4096): Q/K row-major (two contiguous 16MB buffers). n in [4096,6144): V transposed.
__global__ __launch_bounds__(256) void gemm_qkv(const unsigned short* __restrict__ A,
                                                const unsigned short* __restrict__ Bw,
                                                unsigned short* __restrict__ qk,
                                                unsigned short* __restrict__ vt) {
    __shared__ unsigned short sA[128 * 32];
    __shared__ unsigned short sB[128 * 32];
    const int K = DMODEL;
    const int tid = threadIdx.x;
    const int wave = tid >> 6, lane = tid & 63;
    const int m0 = blockIdx.y * 128, n0 = blockIdx.x * 128;
    const int wm = (wave >> 1) * 64, wn = (wave & 1) * 64;

    f32x4 acc[4][4] = {};

    const int srow = wave * 32 + (lane >> 2);
    const int scol = (lane & 3) * 8;
    const unsigned short* Ag = A + (size_t)(m0 + srow) * K + scol;
    const unsigned short* Bg = Bw + (size_t)(n0 + srow) * K + scol;
    unsigned short* sA0 = &sA[(wave * 32) * 32];
    unsigned short* sA1 = &sA[(wave * 32 + 16) * 32];
    unsigned short* sB0 = &sB[(wave * 32) * 32];
    unsigned short* sB1 = &sB[(wave * 32 + 16) * 32];
    const int fr = lane & 15, fo = (lane >> 4) * 8;

    for (int kb = 0; kb < K; kb += 32) {
        gld_lds16(Ag + kb, sA0);
        gld_lds16(Ag + (size_t)16 * K + kb, sA1);
        gld_lds16(Bg + kb, sB0);
        gld_lds16(Bg + (size_t)16 * K + kb, sB1);
        __syncthreads();
        bf16x8 af[4], bfr[4];
        #pragma unroll
        for (int mt = 0; mt < 4; mt++)
            af[mt] = *(const bf16x8*)&sA[(wm + mt * 16 + fr) * 32 + fo];
        #pragma unroll
        for (int nt = 0; nt < 4; nt++)
            bfr[nt] = *(const bf16x8*)&sB[(wn + nt * 16 + fr) * 32 + fo];
        #pragma unroll
        for (int mt = 0; mt < 4; mt++)
            #pragma unroll
            for (int nt = 0; nt < 4; nt++)
                acc[mt][nt] = __builtin_amdgcn_mfma_f32_16x16x32_bf16(af[mt], bfr[nt], acc[mt][nt], 0, 0, 0);
        __syncthreads();
    }

    const int g4 = (lane >> 4) * 4, c0 = lane & 15;
    if (n0 < 4096) {
        #pragma unroll
        for (int mt = 0; mt < 4; mt++)
            #pragma unroll
            for (int nt = 0; nt < 4; nt++) {
                int col = n0 + wn + nt * 16 + c0;
                size_t base = (size_t)(col >> 11) * 8388608 + (size_t)(col & 2047);
                #pragma unroll
                for (int r = 0; r < 4; r++) {
                    int row = m0 + wm + mt * 16 + g4 + r;
                    qk[base + (size_t)row * 2048] = f2b(acc[mt][nt][r]);
                }
            }
    } else {
        #pragma unroll
        for (int mt = 0; mt < 4; mt++) {
            int mbase = m0 + wm + mt * 16 + g4;
            int bb = mbase >> 11;
            int nn = mbase & 2047;
            #pragma unroll
            for (int nt = 0; nt < 4; nt++) {
                int d = n0 - 4096 + wn + nt * 16 + c0;
                union { unsigned short u[4]; uint2 v; } o;
                #pragma unroll
                for (int r = 0; r < 4; r++) o.u[r] = f2b(acc[mt][nt][r]);
                *(uint2*)(vt + ((size_t)(bb * 2048 + d)) * 2048 + nn) = o.v;
            }
        }
    }
}

// ---------------- plain GEMM (fp32 out) for the output projection ----------------
__global__ __launch_bounds__(256) void gemm_out(const unsigned short* __restrict__ A,
                                                const unsigned short* __restrict__ Bw,
                                                float* __restrict__ Cf) {
    __shared__ unsigned short sA[128 * 32];
    __shared__ unsigned short sB[128 * 32];
    const int K = DMODEL, Nn = DMODEL;
    const int tid = threadIdx.x;
    const int wave = tid >> 6, lane = tid & 63;
    const int m0 = blockIdx.y * 128, n0 = blockIdx.x * 128;
    const int wm = (wave >> 1) * 64, wn = (wave & 1) * 64;

    f32x4 acc[4][4] = {};

    const int srow = wave * 32 + (lane >> 2);
    const int scol = (lane & 3) * 8;
    const unsigned short* Ag = A + (size_t)(m0 + srow) * K + scol;
    const unsigned short* Bg = Bw + (size_t)(n0 + srow) * K + scol;
    unsigned short* sA0 = &sA[(wave * 32) * 32];
    unsigned short* sA1 = &sA[(wave * 32 + 16) * 32];
    unsigned short* sB0 = &sB[(wave * 32) * 32];
    unsigned short* sB1 = &sB[(wave * 32 + 16) * 32];
    const int fr = lane & 15, fo = (lane >> 4) * 8;

    for (int kb = 0; kb < K; kb += 32) {
        gld_lds16(Ag + kb, sA0);
        gld_lds16(Ag + (size_t)16 * K + kb, sA1);
        gld_lds16(Bg + kb, sB0);
        gld_lds16(Bg + (size_t)16 * K + kb, sB1);
        __syncthreads();
        bf16x8 af[4], bfr[4];
        #pragma unroll
        for (int mt = 0; mt < 4; mt++)
            af[mt] = *(const bf16x8*)&sA[(wm + mt * 16 + fr) * 32 + fo];
        #pragma unroll
        for (int nt = 0; nt < 4; nt++)
            bfr[nt] = *(const bf16x8*)&sB[(wn + nt * 16 + fr) * 32 + fo];
        #pragma unroll
        for (int mt = 0; mt < 4; mt++)
            #pragma unroll
            for (int nt = 0; nt < 4; nt++)
                acc[mt][nt] = __builtin_amdgcn_mfma_f32_16x16x32_bf16(af[mt], bfr[nt], acc[mt][nt], 0, 0, 0);
        __syncthreads();
    }

    const int g4 = (lane >> 4) * 4, c0 = lane & 15;
    #pragma unroll
    for (int mt = 0; mt < 4; mt++)
        #pragma unroll
        for (int nt = 0; nt < 4; nt++) {
            int col = n0 + wn + nt * 16 + c0;
            #pragma unroll
            for (int r = 0; r < 4; r++) {
                int row = m0 + wm + mt * 16 + g4 + r;
                Cf[(size_t)row * Nn + col] = acc[mt][nt][r];
            }
        }
}

// ---------------- RoPE, vectorized. Q pre-scaled by 1/sqrt(hd). ----------------
__global__ __launch_bounds__(256) void rope_kernel(unsigned short* __restrict__ Q,
                                                   unsigned short* __restrict__ Kb) {
    int t = blockIdx.x * 256 + threadIdx.x;   // 1,048,576 threads
    int dq = t & 15, h = (t >> 4) & 15, m = t >> 8;
    int n = m & (NSEQ - 1);
    size_t base = (size_t)m * DMODEL + h * HD + dq * 4;

    union U4 { unsigned short u[4]; uint2 v; };
    U4 qlo, qhi, klo, khi, oql, oqh, okl, okh;
    qlo.v = *(const uint2*)(Q + base);
    qhi.v = *(const uint2*)(Q + base + 64);
    klo.v = *(const uint2*)(Kb + base);
    khi.v = *(const uint2*)(Kb + base + 64);

    const float scq = 0.08838834764831845f;   // 1/sqrt(128)
    #pragma unroll
    for (int j = 0; j < 4; j++) {
        int d = dq * 4 + j;
        float invf = exp2f((float)d * -0.2076205059304545f);  // 10000^(-d/64)
        float fr = (float)n * invf;
        float sv, cv;
        __sincosf(fr, &sv, &cv);
        float q1 = b2f(qlo.u[j]), q2 = b2f(qhi.u[j]);
        float k1 = b2f(klo.u[j]), k2 = b2f(khi.u[j]);
        oql.u[j] = f2b((q1 * cv - q2 * sv) * scq);
        oqh.u[j] = f2b((q2 * cv + q1 * sv) * scq);
        okl.u[j] = f2b(k1 * cv - k2 * sv);
        okh.u[j] = f2b(k2 * cv + k1 * sv);
    }
    *(uint2*)(Q + base)       = oql.v;
    *(uint2*)(Q + base + 64)  = oqh.v;
    *(uint2*)(Kb + base)      = okl.v;
    *(uint2*)(Kb + base + 64) = okh.v;
}

// ---------------- Flash attention, S^T formulation — R3-verbatim body ----------------
// Grid (32,16): bh on blockIdx.x. Round-robin XCD assignment then gives each XCD
// only bh = xcd (mod 8) slices: 4 MB K/V working set per XCD-L2 (measured-good).
__global__ __launch_bounds__(256) void attn_kernel(const unsigned short* __restrict__ Q,
                                                   const unsigned short* __restrict__ Kg,
                                                   const unsigned short* __restrict__ Vt,
                                                   unsigned short* __restrict__ O) {
    __shared__ unsigned short sK[64 * 136];   // [kv][d], stride 136
    __shared__ unsigned short sV[128 * 88];   // V^T tile [d][kv], stride 88

    const int bh = blockIdx.x;
    const int b = bh >> 4, h = bh & 15;
    const int qt = blockIdx.y;                // 0..15, 128 q-rows each
    const int tid = threadIdx.x, wave = tid >> 6, lane = tid & 63;
    const int c0 = lane & 15, grp = lane >> 4;

    // Q as B-operand fragments: lane holds Q[q = base + c0][d = grp*8+j (+ks*32)]
    bf16x8 qf[2][4];
    {
        const unsigned short* Qbase = Q + (size_t)(b * NSEQ + qt * 128 + wave * 32 + c0) * DMODEL + h * HD + grp * 8;
        #pragma unroll
        for (int nt = 0; nt < 2; nt++)
            #pragma unroll
            for (int ks = 0; ks < 4; ks++)
                qf[nt][ks] = *(const bf16x8*)(Qbase + (size_t)nt * 16 * DMODEL + ks * 32);
    }

    f32x4 oacc[8][2] = {};                    // O^T[d = mo*16+grp*4+r][q = nt*16+c0]
    float lsum[2] = {0.f, 0.f};

    const unsigned short* Kbase = Kg + (size_t)(b * NSEQ) * DMODEL + h * HD;
    const unsigned short* Vbase = Vt + (size_t)(bh * HD) * NSEQ;

    for (int kv0 = 0; kv0 < NSEQ; kv0 += 64) {
        __syncthreads();
        // stage K tile [64][128] -> sK
        #pragma unroll
        for (int i = 0; i < 4; i++) {
            int fl = i * 256 + tid;
            int rr = fl >> 4, cc = fl & 15;
            *(uint4*)&sK[rr * 136 + cc * 8] = *(const uint4*)(Kbase + (size_t)(kv0 + rr) * DMODEL + cc * 8);
        }
        // stage V^T tile [128][64] -> sV
        #pragma unroll
        for (int i = 0; i < 4; i++) {
            int fl = i * 256 + tid;
            int rr = fl >> 3, cc = fl & 7;
            *(uint4*)&sV[rr * 88 + cc * 8] = *(const uint4*)(Vbase + (size_t)rr * NSEQ + kv0 + cc * 8);
        }
        __syncthreads();

        // S^T[kv][q]: A = K rows (m=kv), B = Q rows (n=q)
        f32x4 s[4][2] = {};
        #pragma unroll
        for (int ks = 0; ks < 4; ks++) {
            bf16x8 kf[4];
            #pragma unroll
            for (int mt = 0; mt < 4; mt++)
                kf[mt] = *(const bf16x8*)&sK[(mt * 16 + c0) * 136 + ks * 32 + grp * 8];
            #pragma unroll
            for (int mt = 0; mt < 4; mt++)
                #pragma unroll
                for (int nt = 0; nt < 2; nt++)
                    s[mt][nt] = __builtin_amdgcn_mfma_f32_16x16x32_bf16(kf[mt], qf[nt][ks], s[mt][nt], 0, 0, 0);
        }

        // exp + per-lane row-sum + pack into PV B-fragments (k = grp*4+j)
        bf16x4 pk[4][2];
        #pragma unroll
        for (int mt = 0; mt < 4; mt++)
            #pragma unroll
            for (int nt = 0; nt < 2; nt++) {
                float p0 = __expf(s[mt][nt][0]);
                float p1 = __expf(s[mt][nt][1]);
                float p2 = __expf(s[mt][nt][2]);
                float p3 = __expf(s[mt][nt][3]);
                lsum[nt] += (p0 + p1) + (p2 + p3);
                bf16x4 t;
                t[0] = (short)f2b(p0); t[1] = (short)f2b(p1);
                t[2] = (short)f2b(p2); t[3] = (short)f2b(p3);
                pk[mt][nt] = t;
            }

        // O^T += V^T . P^T  via 16x16x16 MFMA; A-frags (b64) from sV, B-frags in regs
        #pragma unroll
        for (int mtK = 0; mtK < 4; mtK++) {
            bf16x4 va[8];
            #pragma unroll
            for (int mo = 0; mo < 8; mo++)
                va[mo] = *(const bf16x4*)&sV[(mo * 16 + c0) * 88 + mtK * 16 + grp * 4];
            #pragma unroll
            for (int mo = 0; mo < 8; mo++)
                #pragma unroll
                for (int nt = 0; nt < 2; nt++)
                    oacc[mo][nt] = __builtin_amdgcn_mfma_f32_16x16x16bf16_1k(va[mo], pk[mtK][nt], oacc[mo][nt], 0, 0, 0);
        }
    }

    // epilogue: cross-grp sum reduce, normalize, store
    float invl[2];
    #pragma unroll
    for (int nt = 0; nt < 2; nt++) {
        float li = lsum[nt];
        li += __shfl_xor(li, 16);
        li += __shfl_xor(li, 32);
        invl[nt] = 1.0f / li;
    }
    #pragma unroll
    for (int mo = 0; mo < 8; mo++)
        #pragma unroll
        for (int nt = 0; nt < 2; nt++) {
            union { unsigned short u[4]; uint2 v; } o;
            #pragma unroll
            for (int r = 0; r < 4; r++)
                o.u[r] = f2b(oacc[mo][nt][r] * invl[nt]);
            int row = b * NSEQ + qt * 128 + wave * 32 + nt * 16 + c0;
            int col = h * HD + mo * 16 + grp * 4;
            *(uint2*)(O + (size_t)row * DMODEL + col) = o.v;
        }
}

extern "C" void kernel_launch(void* const* d_in, const int* in_sizes, int n_in,
                              void* d_out, int out_size, void* d_ws, size_t ws_size,
                              hipStream_t stream) {
    const float* x  = (const float*)d_in[0];
    const float* Wq = (const float*)d_in[1];
    const float* Wk = (const float*)d_in[2];
    const float* Wv = (const float*)d_in[3];
    const float* Wo = (const float*)d_in[4];

    char* ws = (char*)d_ws;
    // xb(16M, reused as attn O) | wqb..wob (4x8M contiguous) | qb(16M)+kb(16M) contiguous | vt(16M)
    unsigned short* xb  = (unsigned short*)(ws);
    unsigned short* wqb = (unsigned short*)(ws + 16777216);
    unsigned short* wob = (unsigned short*)(ws + 16777216 + 3 * 8388608);
    unsigned short* qb  = (unsigned short*)(ws + 50331648);
    unsigned short* kb  = (unsigned short*)(ws + 67108864);
    unsigned short* vt  = (unsigned short*)(ws + 83886080);

    cast_all_kernel<<<12288, 256, 0, stream>>>(x, Wq, Wk, Wv, Wo, xb, wqb);

    gemm_qkv<<<dim3(48, 32), 256, 0, stream>>>(xb, wqb, qb, vt);

    rope_kernel<<<4096, 256, 0, stream>>>(qb, kb);

    attn_kernel<<<dim3(32, 16), 256, 0, stream>>>(qb, kb, vt, xb);

    gemm_out<<<dim3(16, 32), 256, 0, stream>>>(xb, wob, (float*)d_out);
}

// Round 7
// 414.792 us; speedup vs baseline: 1.1136x; 1.0199x over previous
//
#include <hip/hip_runtime.h>
#include <hip/hip_bf16.h>
#include <math.h>

typedef short bf16x8 __attribute__((ext_vector_type(8)));
typedef short bf16x4 __attribute__((ext_vector_type(4)));
typedef float f32x4 __attribute__((ext_vector_type(4)));

#define NSEQ 2048
#define DMODEL 2048
#define NH 16
#define HD 128
#define BATCH 2
#define MROWS 4096  // BATCH*NSEQ

__device__ __forceinline__ unsigned short f2b(float f) {
    __hip_bfloat16 h = __float2bfloat16(f);
    return *reinterpret_cast<unsigned short*>(&h);
}
__device__ __forceinline__ float b2f(unsigned short u) {
    __hip_bfloat16 h;
    *reinterpret_cast<unsigned short*>(&h) = u;
    return __bfloat162float(h);
}

__device__ __forceinline__ void gld_lds16(const unsigned short* g, unsigned short* l) {
    __builtin_amdgcn_global_load_lds(
        (const __attribute__((address_space(1))) unsigned int*)(const void*)g,
        (__attribute__((address_space(3))) unsigned int*)(void*)l,
        16, 0, 0);
}

// ---------------- fused cast fp32 -> bf16 for x + 4 weights ----------------
__global__ __launch_bounds__(256) void cast_all_kernel(const float* __restrict__ x,
                                                       const float* __restrict__ wq,
                                                       const float* __restrict__ wk,
                                                       const float* __restrict__ wv,
                                                       const float* __restrict__ wo,
                                                       unsigned short* __restrict__ xb,
                                                       unsigned short* __restrict__ wqb) {
    int bid = blockIdx.x;
    const float* src;
    unsigned short* dst;
    int off;
    if (bid < 4096) {
        src = x; dst = xb; off = bid;
    } else {
        int w = (bid - 4096) >> 11;
        src = (w == 0) ? wq : (w == 1) ? wk : (w == 2) ? wv : wo;
        dst = wqb + (size_t)w * 4194304;
        off = (bid - 4096) & 2047;
    }
    int i = (off * 256 + threadIdx.x) * 8;
    float4 a = *(const float4*)(src + i);
    float4 b = *(const float4*)(src + i + 4);
    union { unsigned short u[8]; uint4 v; } tmp;
    tmp.u[0] = f2b(a.x); tmp.u[1] = f2b(a.y); tmp.u[2] = f2b(a.z); tmp.u[3] = f2b(a.w);
    tmp.u[4] = f2b(b.x); tmp.u[5] = f2b(b.y); tmp.u[6] = f2b(b.z); tmp.u[7] = f2b(b.w);
    *(uint4*)(dst + i) = tmp.v;
}

// ---------------- QKV GEMM + fused RoPE ----------------
// A[4096][2048] x W[6144][2048]^T. Wave tiling 32x128: each wave owns full 128-col
// head tile, so RoPE pair (d, d+64) = (acc[mt][nt], acc[mt][nt+4]) is in-register.
// n0 in [0,2048): Q (RoPE + 1/sqrt(hd) scale); [2048,4096): K (RoPE);
// [4096,6144): V stored transposed into vt.
__global__ __launch_bounds__(256) void gemm_qkv(const unsigned short* __restrict__ A,
                                                const unsigned short* __restrict__ Bw,
                                                unsigned short* __restrict__ qk,
                                                unsigned short* __restrict__ vt) {
    __shared__ unsigned short sA[128 * 32];
    __shared__ unsigned short sB[128 * 32];
    const int K = DMODEL;
    const int tid = threadIdx.x;
    const int wave = tid >> 6, lane = tid & 63;
    const int m0 = blockIdx.y * 128, n0 = blockIdx.x * 128;
    const int wm = wave * 32;                 // 32 rows x 128 cols per wave

    f32x4 acc[2][8] = {};

    const int srow = wave * 32 + (lane >> 2);
    const int scol = (lane & 3) * 8;
    const unsigned short* Ag = A + (size_t)(m0 + srow) * K + scol;
    const unsigned short* Bg = Bw + (size_t)(n0 + srow) * K + scol;
    unsigned short* sA0 = &sA[(wave * 32) * 32];
    unsigned short* sA1 = &sA[(wave * 32 + 16) * 32];
    unsigned short* sB0 = &sB[(wave * 32) * 32];
    unsigned short* sB1 = &sB[(wave * 32 + 16) * 32];
    const int fr = lane & 15, fo = (lane >> 4) * 8;

    for (int kb = 0; kb < K; kb += 32) {
        gld_lds16(Ag + kb, sA0);
        gld_lds16(Ag + (size_t)16 * K + kb, sA1);
        gld_lds16(Bg + kb, sB0);
        gld_lds16(Bg + (size_t)16 * K + kb, sB1);
        __syncthreads();
        bf16x8 af[2], bfr[8];
        #pragma unroll
        for (int mt = 0; mt < 2; mt++)
            af[mt] = *(const bf16x8*)&sA[(wm + mt * 16 + fr) * 32 + fo];
        #pragma unroll
        for (int nt = 0; nt < 8; nt++)
            bfr[nt] = *(const bf16x8*)&sB[(nt * 16 + fr) * 32 + fo];
        #pragma unroll
        for (int mt = 0; mt < 2; mt++)
            #pragma unroll
            for (int nt = 0; nt < 8; nt++)
                acc[mt][nt] = __builtin_amdgcn_mfma_f32_16x16x32_bf16(af[mt], bfr[nt], acc[mt][nt], 0, 0, 0);
        __syncthreads();
    }

    const int g4 = (lane >> 4) * 4, c0 = lane & 15;
    if (n0 < 4096) {
        // Q or K with fused RoPE. Tile = exactly one head (128 cols).
        const float scale = (n0 < 2048) ? 0.08838834764831845f : 1.0f;  // 1/sqrt(128) for Q
        unsigned short* dst = qk + (size_t)(n0 >> 11) * 8388608;
        const int colbase = n0 & 2047;
        float invf[4];
        #pragma unroll
        for (int nt = 0; nt < 4; nt++)
            invf[nt] = exp2f((float)(nt * 16 + c0) * -0.2076205059304545f);  // 10000^(-d/64)
        #pragma unroll
        for (int mt = 0; mt < 2; mt++) {
            #pragma unroll
            for (int r = 0; r < 4; r++) {
                int row = m0 + wm + mt * 16 + g4 + r;
                float nf = (float)(row & (NSEQ - 1));
                size_t rbase = (size_t)row * 2048 + colbase + c0;
                #pragma unroll
                for (int nt = 0; nt < 4; nt++) {
                    float sv, cv;
                    __sincosf(nf * invf[nt], &sv, &cv);
                    float lo = acc[mt][nt][r], hi = acc[mt][nt + 4][r];
                    dst[rbase + nt * 16]      = f2b((lo * cv - hi * sv) * scale);
                    dst[rbase + nt * 16 + 64] = f2b((hi * cv + lo * sv) * scale);
                }
            }
        }
    } else {
        // V transposed: vt[(b*2048 + d)][n]
        #pragma unroll
        for (int mt = 0; mt < 2; mt++) {
            int mbase = m0 + wm + mt * 16 + g4;
            int bb = mbase >> 11;
            int nn = mbase & 2047;
            #pragma unroll
            for (int nt = 0; nt < 8; nt++) {
                int d = n0 - 4096 + nt * 16 + c0;
                union { unsigned short u[4]; uint2 v; } o;
                #pragma unroll
                for (int r = 0; r < 4; r++) o.u[r] = f2b(acc[mt][nt][r]);
                *(uint2*)(vt + ((size_t)(bb * 2048 + d)) * 2048 + nn) = o.v;
            }
        }
    }
}

// ---------------- output projection (fp32 out), 64x128 tiles -> 1024 blocks ----------------
__global__ __launch_bounds__(256) void gemm_out(const unsigned short* __restrict__ A,
                                                const unsigned short* __restrict__ Bw,
                                                float* __restrict__ Cf) {
    __shared__ unsigned short sA[64 * 32];
    __shared__ unsigned short sB[128 * 32];
    const int K = DMODEL, Nn = DMODEL;
    const int tid = threadIdx.x;
    const int wave = tid >> 6, lane = tid & 63;
    const int m0 = blockIdx.y * 64, n0 = blockIdx.x * 128;
    const int wm = (wave >> 1) * 32, wn = (wave & 1) * 64;

    f32x4 acc[2][4] = {};

    const int srowA = wave * 16 + (lane >> 2);
    const int srowB = wave * 32 + (lane >> 2);
    const int scol = (lane & 3) * 8;
    const unsigned short* Ag = A + (size_t)(m0 + srowA) * K + scol;
    const unsigned short* Bg = Bw + (size_t)(n0 + srowB) * K + scol;
    unsigned short* sA0 = &sA[(wave * 16) * 32];
    unsigned short* sB0 = &sB[(wave * 32) * 32];
    unsigned short* sB1 = &sB[(wave * 32 + 16) * 32];
    const int fr = lane & 15, fo = (lane >> 4) * 8;

    for (int kb = 0; kb < K; kb += 32) {
        gld_lds16(Ag + kb, sA0);
        gld_lds16(Bg + kb, sB0);
        gld_lds16(Bg + (size_t)16 * K + kb, sB1);
        __syncthreads();
        bf16x8 af[2], bfr[4];
        #pragma unroll
        for (int mt = 0; mt < 2; mt++)
            af[mt] = *(const bf16x8*)&sA[(wm + mt * 16 + fr) * 32 + fo];
        #pragma unroll
        for (int nt = 0; nt < 4; nt++)
            bfr[nt] = *(const bf16x8*)&sB[(wn + nt * 16 + fr) * 32 + fo];
        #pragma unroll
        for (int mt = 0; mt < 2; mt++)
            #pragma unroll
            for (int nt = 0; nt < 4; nt++)
                acc[mt][nt] = __builtin_amdgcn_mfma_f32_16x16x32_bf16(af[mt], bfr[nt], acc[mt][nt], 0, 0, 0);
        __syncthreads();
    }

    const int g4 = (lane >> 4) * 4, c0 = lane & 15;
    #pragma unroll
    for (int mt = 0; mt < 2; mt++)
        #pragma unroll
        for (int nt = 0; nt < 4; nt++) {
            int col = n0 + wn + nt * 16 + c0;
            #pragma unroll
            for (int r = 0; r < 4; r++) {
                int row = m0 + wm + mt * 16 + g4 + r;
                Cf[(size_t)row * Nn + col] = acc[mt][nt][r];
            }
        }
}

// ---------------- Flash attention, S^T formulation — R3/R6-verbatim body ----------------
// Grid (32,16): bh on blockIdx.x -> each XCD sees bh = xcd (mod 8): 4 MB K/V per XCD-L2.
__global__ __launch_bounds__(256) void attn_kernel(const unsigned short* __restrict__ Q,
                                                   const unsigned short* __restrict__ Kg,
                                                   const unsigned short* __restrict__ Vt,
                                                   unsigned short* __restrict__ O) {
    __shared__ unsigned short sK[64 * 136];   // [kv][d], stride 136
    __shared__ unsigned short sV[128 * 88];   // V^T tile [d][kv], stride 88

    const int bh = blockIdx.x;
    const int b = bh >> 4, h = bh & 15;
    const int qt = blockIdx.y;                // 0..15, 128 q-rows each
    const int tid = threadIdx.x, wave = tid >> 6, lane = tid & 63;
    const int c0 = lane & 15, grp = lane >> 4;

    bf16x8 qf[2][4];
    {
        const unsigned short* Qbase = Q + (size_t)(b * NSEQ + qt * 128 + wave * 32 + c0) * DMODEL + h * HD + grp * 8;
        #pragma unroll
        for (int nt = 0; nt < 2; nt++)
            #pragma unroll
            for (int ks = 0; ks < 4; ks++)
                qf[nt][ks] = *(const bf16x8*)(Qbase + (size_t)nt * 16 * DMODEL + ks * 32);
    }

    f32x4 oacc[8][2] = {};                    // O^T[d = mo*16+grp*4+r][q = nt*16+c0]
    float lsum[2] = {0.f, 0.f};

    const unsigned short* Kbase = Kg + (size_t)(b * NSEQ) * DMODEL + h * HD;
    const unsigned short* Vbase = Vt + (size_t)(bh * HD) * NSEQ;

    for (int kv0 = 0; kv0 < NSEQ; kv0 += 64) {
        __syncthreads();
        #pragma unroll
        for (int i = 0; i < 4; i++) {
            int fl = i * 256 + tid;
            int rr = fl >> 4, cc = fl & 15;
            *(uint4*)&sK[rr * 136 + cc * 8] = *(const uint4*)(Kbase + (size_t)(kv0 + rr) * DMODEL + cc * 8);
        }
        #pragma unroll
        for (int i = 0; i < 4; i++) {
            int fl = i * 256 + tid;
            int rr = fl >> 3, cc = fl & 7;
            *(uint4*)&sV[rr * 88 + cc * 8] = *(const uint4*)(Vbase + (size_t)rr * NSEQ + kv0 + cc * 8);
        }
        __syncthreads();

        f32x4 s[4][2] = {};
        #pragma unroll
        for (int ks = 0; ks < 4; ks++) {
            bf16x8 kf[4];
            #pragma unroll
            for (int mt = 0; mt < 4; mt++)
                kf[mt] = *(const bf16x8*)&sK[(mt * 16 + c0) * 136 + ks * 32 + grp * 8];
            #pragma unroll
            for (int mt = 0; mt < 4; mt++)
                #pragma unroll
                for (int nt = 0; nt < 2; nt++)
                    s[mt][nt] = __builtin_amdgcn_mfma_f32_16x16x32_bf16(kf[mt], qf[nt][ks], s[mt][nt], 0, 0, 0);
        }

        bf16x4 pk[4][2];
        #pragma unroll
        for (int mt = 0; mt < 4; mt++)
            #pragma unroll
            for (int nt = 0; nt < 2; nt++) {
                float p0 = __expf(s[mt][nt][0]);
                float p1 = __expf(s[mt][nt][1]);
                float p2 = __expf(s[mt][nt][2]);
                float p3 = __expf(s[mt][nt][3]);
                lsum[nt] += (p0 + p1) + (p2 + p3);
                bf16x4 t;
                t[0] = (short)f2b(p0); t[1] = (short)f2b(p1);
                t[2] = (short)f2b(p2); t[3] = (short)f2b(p3);
                pk[mt][nt] = t;
            }

        #pragma unroll
        for (int mtK = 0; mtK < 4; mtK++) {
            bf16x4 va[8];
            #pragma unroll
            for (int mo = 0; mo < 8; mo++)
                va[mo] = *(const bf16x4*)&sV[(mo * 16 + c0) * 88 + mtK * 16 + grp * 4];
            #pragma unroll
            for (int mo = 0; mo < 8; mo++)
                #pragma unroll
                for (int nt = 0; nt < 2; nt++)
                    oacc[mo][nt] = __builtin_amdgcn_mfma_f32_16x16x16bf16_1k(va[mo], pk[mtK][nt], oacc[mo][nt], 0, 0, 0);
        }
    }

    float invl[2];
    #pragma unroll
    for (int nt = 0; nt < 2; nt++) {
        float li = lsum[nt];
        li += __shfl_xor(li, 16);
        li += __shfl_xor(li, 32);
        invl[nt] = 1.0f / li;
    }
    #pragma unroll
    for (int mo = 0; mo < 8; mo++)
        #pragma unroll
        for (int nt = 0; nt < 2; nt++) {
            union { unsigned short u[4]; uint2 v; } o;
            #pragma unroll
            for (int r = 0; r < 4; r++)
                o.u[r] = f2b(oacc[mo][nt][r] * invl[nt]);
            int row = b * NSEQ + qt * 128 + wave * 32 + nt * 16 + c0;
            int col = h * HD + mo * 16 + grp * 4;
            *(uint2*)(O + (size_t)row * DMODEL + col) = o.v;
        }
}

extern "C" void kernel_launch(void* const* d_in, const int* in_sizes, int n_in,
                              void* d_out, int out_size, void* d_ws, size_t ws_size,
                              hipStream_t stream) {
    const float* x  = (const float*)d_in[0];
    const float* Wq = (const float*)d_in[1];
    const float* Wk = (const float*)d_in[2];
    const float* Wv = (const float*)d_in[3];
    const float* Wo = (const float*)d_in[4];

    char* ws = (char*)d_ws;
    // xb(16M, reused as attn O) | wqb..wob (4x8M contiguous) | qb(16M)+kb(16M) contiguous | vt(16M)
    unsigned short* xb  = (unsigned short*)(ws);
    unsigned short* wqb = (unsigned short*)(ws + 16777216);
    unsigned short* wob = (unsigned short*)(ws + 16777216 + 3 * 8388608);
    unsigned short* qb  = (unsigned short*)(ws + 50331648);
    unsigned short* kb  = (unsigned short*)(ws + 67108864);
    unsigned short* vt  = (unsigned short*)(ws + 83886080);

    cast_all_kernel<<<12288, 256, 0, stream>>>(x, Wq, Wk, Wv, Wo, xb, wqb);

    gemm_qkv<<<dim3(48, 32), 256, 0, stream>>>(xb, wqb, qb, vt);

    attn_kernel<<<dim3(32, 16), 256, 0, stream>>>(qb, kb, vt, xb);

    gemm_out<<<dim3(16, 64), 256, 0, stream>>>(xb, wob, (float*)d_out);
}

// Round 8
// 388.792 us; speedup vs baseline: 1.1880x; 1.0669x over previous
//
#include <hip/hip_runtime.h>
#include <hip/hip_bf16.h>
#include <math.h>

typedef short bf16x8 __attribute__((ext_vector_type(8)));
typedef short bf16x4 __attribute__((ext_vector_type(4)));
typedef float f32x4 __attribute__((ext_vector_type(4)));

#define NSEQ 2048
#define DMODEL 2048
#define NH 16
#define HD 128
#define BATCH 2
#define MROWS 4096  // BATCH*NSEQ

__device__ __forceinline__ unsigned short f2b(float f) {
    __hip_bfloat16 h = __float2bfloat16(f);
    return *reinterpret_cast<unsigned short*>(&h);
}
__device__ __forceinline__ float b2f(unsigned short u) {
    __hip_bfloat16 h;
    *reinterpret_cast<unsigned short*>(&h) = u;
    return __bfloat162float(h);
}

__device__ __forceinline__ void gld_lds16(const unsigned short* g, unsigned short* l) {
    __builtin_amdgcn_global_load_lds(
        (const __attribute__((address_space(1))) unsigned int*)(const void*)g,
        (__attribute__((address_space(3))) unsigned int*)(void*)l,
        16, 0, 0);
}

// ---------------- fused cast fp32 -> bf16 for x + 4 weights (HBM-roofline) ----------------
__global__ __launch_bounds__(256) void cast_all_kernel(const float* __restrict__ x,
                                                       const float* __restrict__ wq,
                                                       const float* __restrict__ wk,
                                                       const float* __restrict__ wv,
                                                       const float* __restrict__ wo,
                                                       unsigned short* __restrict__ xb,
                                                       unsigned short* __restrict__ wqb) {
    int bid = blockIdx.x;
    const float* src;
    unsigned short* dst;
    int off;
    if (bid < 4096) {
        src = x; dst = xb; off = bid;
    } else {
        int w = (bid - 4096) >> 11;
        src = (w == 0) ? wq : (w == 1) ? wk : (w == 2) ? wv : wo;
        dst = wqb + (size_t)w * 4194304;
        off = (bid - 4096) & 2047;
    }
    int i = (off * 256 + threadIdx.x) * 8;
    float4 a = *(const float4*)(src + i);
    float4 b = *(const float4*)(src + i + 4);
    union { unsigned short u[8]; uint4 v; } tmp;
    tmp.u[0] = f2b(a.x); tmp.u[1] = f2b(a.y); tmp.u[2] = f2b(a.z); tmp.u[3] = f2b(a.w);
    tmp.u[4] = f2b(b.x); tmp.u[5] = f2b(b.y); tmp.u[6] = f2b(b.z); tmp.u[7] = f2b(b.w);
    *(uint4*)(dst + i) = tmp.v;
}

// ---------------- QKV GEMM + fused RoPE (unchanged, measured 135 us / 763 TF) ----------------
__global__ __launch_bounds__(256) void gemm_qkv(const unsigned short* __restrict__ A,
                                                const unsigned short* __restrict__ Bw,
                                                unsigned short* __restrict__ qk,
                                                unsigned short* __restrict__ vt) {
    __shared__ unsigned short sA[128 * 32];
    __shared__ unsigned short sB[128 * 32];
    const int K = DMODEL;
    const int tid = threadIdx.x;
    const int wave = tid >> 6, lane = tid & 63;
    const int m0 = blockIdx.y * 128, n0 = blockIdx.x * 128;
    const int wm = wave * 32;                 // 32 rows x 128 cols per wave

    f32x4 acc[2][8] = {};

    const int srow = wave * 32 + (lane >> 2);
    const int scol = (lane & 3) * 8;
    const unsigned short* Ag = A + (size_t)(m0 + srow) * K + scol;
    const unsigned short* Bg = Bw + (size_t)(n0 + srow) * K + scol;
    unsigned short* sA0 = &sA[(wave * 32) * 32];
    unsigned short* sA1 = &sA[(wave * 32 + 16) * 32];
    unsigned short* sB0 = &sB[(wave * 32) * 32];
    unsigned short* sB1 = &sB[(wave * 32 + 16) * 32];
    const int fr = lane & 15, fo = (lane >> 4) * 8;

    for (int kb = 0; kb < K; kb += 32) {
        gld_lds16(Ag + kb, sA0);
        gld_lds16(Ag + (size_t)16 * K + kb, sA1);
        gld_lds16(Bg + kb, sB0);
        gld_lds16(Bg + (size_t)16 * K + kb, sB1);
        __syncthreads();
        bf16x8 af[2], bfr[8];
        #pragma unroll
        for (int mt = 0; mt < 2; mt++)
            af[mt] = *(const bf16x8*)&sA[(wm + mt * 16 + fr) * 32 + fo];
        #pragma unroll
        for (int nt = 0; nt < 8; nt++)
            bfr[nt] = *(const bf16x8*)&sB[(nt * 16 + fr) * 32 + fo];
        #pragma unroll
        for (int mt = 0; mt < 2; mt++)
            #pragma unroll
            for (int nt = 0; nt < 8; nt++)
                acc[mt][nt] = __builtin_amdgcn_mfma_f32_16x16x32_bf16(af[mt], bfr[nt], acc[mt][nt], 0, 0, 0);
        __syncthreads();
    }

    const int g4 = (lane >> 4) * 4, c0 = lane & 15;
    if (n0 < 4096) {
        const float scale = (n0 < 2048) ? 0.08838834764831845f : 1.0f;  // 1/sqrt(128) for Q
        unsigned short* dst = qk + (size_t)(n0 >> 11) * 8388608;
        const int colbase = n0 & 2047;
        float invf[4];
        #pragma unroll
        for (int nt = 0; nt < 4; nt++)
            invf[nt] = exp2f((float)(nt * 16 + c0) * -0.2076205059304545f);  // 10000^(-d/64)
        #pragma unroll
        for (int mt = 0; mt < 2; mt++) {
            #pragma unroll
            for (int r = 0; r < 4; r++) {
                int row = m0 + wm + mt * 16 + g4 + r;
                float nf = (float)(row & (NSEQ - 1));
                size_t rbase = (size_t)row * 2048 + colbase + c0;
                #pragma unroll
                for (int nt = 0; nt < 4; nt++) {
                    float sv, cv;
                    __sincosf(nf * invf[nt], &sv, &cv);
                    float lo = acc[mt][nt][r], hi = acc[mt][nt + 4][r];
                    dst[rbase + nt * 16]      = f2b((lo * cv - hi * sv) * scale);
                    dst[rbase + nt * 16 + 64] = f2b((hi * cv + lo * sv) * scale);
                }
            }
        }
    } else {
        #pragma unroll
        for (int mt = 0; mt < 2; mt++) {
            int mbase = m0 + wm + mt * 16 + g4;
            int bb = mbase >> 11;
            int nn = mbase & 2047;
            #pragma unroll
            for (int nt = 0; nt < 8; nt++) {
                int d = n0 - 4096 + nt * 16 + c0;
                union { unsigned short u[4]; uint2 v; } o;
                #pragma unroll
                for (int r = 0; r < 4; r++) o.u[r] = f2b(acc[mt][nt][r]);
                *(uint2*)(vt + ((size_t)(bb * 2048 + d)) * 2048 + nn) = o.v;
            }
        }
    }
}

// ---------------- output projection: 128x128 tile, BK=64, swizzled staging ----------------
// Grid-limited to 2 blocks/CU (512 blocks), so 32KB LDS costs nothing; BK=64 halves
// barrier count (32 MFMA : 8 stage : 2 barriers per iter). XOR-swizzle on the GLOBAL
// fetch side (LDS dest of global_load_lds must stay contiguous) kills the stride-128B
// read conflicts: chunk' = chunk ^ (row&7) -> 16 read lanes spread over all 32 banks.
__global__ __launch_bounds__(256) void gemm_out(const unsigned short* __restrict__ A,
                                                const unsigned short* __restrict__ Bw,
                                                float* __restrict__ Cf) {
    __shared__ unsigned short sA[128 * 64];
    __shared__ unsigned short sB[128 * 64];
    const int K = DMODEL, Nn = DMODEL;
    const int tid = threadIdx.x;
    const int wave = tid >> 6, lane = tid & 63;
    const int m0 = blockIdx.y * 128, n0 = blockIdx.x * 128;
    const int wm = (wave >> 1) * 64, wn = (wave & 1) * 64;

    f32x4 acc[4][4] = {};

    // staging: each gld_lds covers 8 rows/wave-quarter: row = i*32 + wave*8 + (lane>>3),
    // fetched global k-chunk = (lane&7) ^ (row&7)  [row&7 == (lane>>3)&7 here]
    const int srowoff = wave * 8 + (lane >> 3);
    const int gchunk = ((lane & 7) ^ ((lane >> 3) & 7)) * 8;
    const unsigned short* Ag = A + (size_t)(m0 + srowoff) * K + gchunk;
    const unsigned short* Bg = Bw + (size_t)(n0 + srowoff) * K + gchunk;
    unsigned short* sAw = &sA[(wave * 8) * 64];
    unsigned short* sBw = &sB[(wave * 8) * 64];

    const int fr = lane & 15, grp = lane >> 4;
    const int swz = fr & 7;

    for (int kb = 0; kb < K; kb += 64) {
        #pragma unroll
        for (int i = 0; i < 4; i++)
            gld_lds16(Ag + (size_t)(i * 32) * K + kb, sAw + i * 32 * 64);
        #pragma unroll
        for (int i = 0; i < 4; i++)
            gld_lds16(Bg + (size_t)(i * 32) * K + kb, sBw + i * 32 * 64);
        __syncthreads();
        #pragma unroll
        for (int ks = 0; ks < 2; ks++) {
            bf16x8 af[4], bfr[4];
            #pragma unroll
            for (int mt = 0; mt < 4; mt++)
                af[mt] = *(const bf16x8*)&sA[(wm + mt * 16 + fr) * 64 + (((ks * 4 + grp) ^ swz) << 3)];
            #pragma unroll
            for (int nt = 0; nt < 4; nt++)
                bfr[nt] = *(const bf16x8*)&sB[(wn + nt * 16 + fr) * 64 + (((ks * 4 + grp) ^ swz) << 3)];
            #pragma unroll
            for (int mt = 0; mt < 4; mt++)
                #pragma unroll
                for (int nt = 0; nt < 4; nt++)
                    acc[mt][nt] = __builtin_amdgcn_mfma_f32_16x16x32_bf16(af[mt], bfr[nt], acc[mt][nt], 0, 0, 0);
        }
        __syncthreads();
    }

    const int g4 = (lane >> 4) * 4, c0 = lane & 15;
    #pragma unroll
    for (int mt = 0; mt < 4; mt++)
        #pragma unroll
        for (int nt = 0; nt < 4; nt++) {
            int col = n0 + wn + nt * 16 + c0;
            #pragma unroll
            for (int r = 0; r < 4; r++) {
                int row = m0 + wm + mt * 16 + g4 + r;
                Cf[(size_t)row * Nn + col] = acc[mt][nt][r];
            }
        }
}

// ---------------- Flash attention, S^T formulation (unchanged, measured-good) ----------------
__global__ __launch_bounds__(256) void attn_kernel(const unsigned short* __restrict__ Q,
                                                   const unsigned short* __restrict__ Kg,
                                                   const unsigned short* __restrict__ Vt,
                                                   unsigned short* __restrict__ O) {
    __shared__ unsigned short sK[64 * 136];   // [kv][d], stride 136
    __shared__ unsigned short sV[128 * 88];   // V^T tile [d][kv], stride 88

    const int bh = blockIdx.x;
    const int b = bh >> 4, h = bh & 15;
    const int qt = blockIdx.y;                // 0..15, 128 q-rows each
    const int tid = threadIdx.x, wave = tid >> 6, lane = tid & 63;
    const int c0 = lane & 15, grp = lane >> 4;

    bf16x8 qf[2][4];
    {
        const unsigned short* Qbase = Q + (size_t)(b * NSEQ + qt * 128 + wave * 32 + c0) * DMODEL + h * HD + grp * 8;
        #pragma unroll
        for (int nt = 0; nt < 2; nt++)
            #pragma unroll
            for (int ks = 0; ks < 4; ks++)
                qf[nt][ks] = *(const bf16x8*)(Qbase + (size_t)nt * 16 * DMODEL + ks * 32);
    }

    f32x4 oacc[8][2] = {};                    // O^T[d = mo*16+grp*4+r][q = nt*16+c0]
    float lsum[2] = {0.f, 0.f};

    const unsigned short* Kbase = Kg + (size_t)(b * NSEQ) * DMODEL + h * HD;
    const unsigned short* Vbase = Vt + (size_t)(bh * HD) * NSEQ;

    for (int kv0 = 0; kv0 < NSEQ; kv0 += 64) {
        __syncthreads();
        #pragma unroll
        for (int i = 0; i < 4; i++) {
            int fl = i * 256 + tid;
            int rr = fl >> 4, cc = fl & 15;
            *(uint4*)&sK[rr * 136 + cc * 8] = *(const uint4*)(Kbase + (size_t)(kv0 + rr) * DMODEL + cc * 8);
        }
        #pragma unroll
        for (int i = 0; i < 4; i++) {
            int fl = i * 256 + tid;
            int rr = fl >> 3, cc = fl & 7;
            *(uint4*)&sV[rr * 88 + cc * 8] = *(const uint4*)(Vbase + (size_t)rr * NSEQ + kv0 + cc * 8);
        }
        __syncthreads();

        f32x4 s[4][2] = {};
        #pragma unroll
        for (int ks = 0; ks < 4; ks++) {
            bf16x8 kf[4];
            #pragma unroll
            for (int mt = 0; mt < 4; mt++)
                kf[mt] = *(const bf16x8*)&sK[(mt * 16 + c0) * 136 + ks * 32 + grp * 8];
            #pragma unroll
            for (int mt = 0; mt < 4; mt++)
                #pragma unroll
                for (int nt = 0; nt < 2; nt++)
                    s[mt][nt] = __builtin_amdgcn_mfma_f32_16x16x32_bf16(kf[mt], qf[nt][ks], s[mt][nt], 0, 0, 0);
        }

        bf16x4 pk[4][2];
        #pragma unroll
        for (int mt = 0; mt < 4; mt++)
            #pragma unroll
            for (int nt = 0; nt < 2; nt++) {
                float p0 = __expf(s[mt][nt][0]);
                float p1 = __expf(s[mt][nt][1]);
                float p2 = __expf(s[mt][nt][2]);
                float p3 = __expf(s[mt][nt][3]);
                lsum[nt] += (p0 + p1) + (p2 + p3);
                bf16x4 t;
                t[0] = (short)f2b(p0); t[1] = (short)f2b(p1);
                t[2] = (short)f2b(p2); t[3] = (short)f2b(p3);
                pk[mt][nt] = t;
            }

        #pragma unroll
        for (int mtK = 0; mtK < 4; mtK++) {
            bf16x4 va[8];
            #pragma unroll
            for (int mo = 0; mo < 8; mo++)
                va[mo] = *(const bf16x4*)&sV[(mo * 16 + c0) * 88 + mtK * 16 + grp * 4];
            #pragma unroll
            for (int mo = 0; mo < 8; mo++)
                #pragma unroll
                for (int nt = 0; nt < 2; nt++)
                    oacc[mo][nt] = __builtin_amdgcn_mfma_f32_16x16x16bf16_1k(va[mo], pk[mtK][nt], oacc[mo][nt], 0, 0, 0);
        }
    }

    float invl[2];
    #pragma unroll
    for (int nt = 0; nt < 2; nt++) {
        float li = lsum[nt];
        li += __shfl_xor(li, 16);
        li += __shfl_xor(li, 32);
        invl[nt] = 1.0f / li;
    }
    #pragma unroll
    for (int mo = 0; mo < 8; mo++)
        #pragma unroll
        for (int nt = 0; nt < 2; nt++) {
            union { unsigned short u[4]; uint2 v; } o;
            #pragma unroll
            for (int r = 0; r < 4; r++)
                o.u[r] = f2b(oacc[mo][nt][r] * invl[nt]);
            int row = b * NSEQ + qt * 128 + wave * 32 + nt * 16 + c0;
            int col = h * HD + mo * 16 + grp * 4;
            *(uint2*)(O + (size_t)row * DMODEL + col) = o.v;
        }
}

extern "C" void kernel_launch(void* const* d_in, const int* in_sizes, int n_in,
                              void* d_out, int out_size, void* d_ws, size_t ws_size,
                              hipStream_t stream) {
    const float* x  = (const float*)d_in[0];
    const float* Wq = (const float*)d_in[1];
    const float* Wk = (const float*)d_in[2];
    const float* Wv = (const float*)d_in[3];
    const float* Wo = (const float*)d_in[4];

    char* ws = (char*)d_ws;
    // xb(16M, reused as attn O) | wqb..wob (4x8M contiguous) | qb(16M)+kb(16M) contiguous | vt(16M)
    unsigned short* xb  = (unsigned short*)(ws);
    unsigned short* wqb = (unsigned short*)(ws + 16777216);
    unsigned short* wob = (unsigned short*)(ws + 16777216 + 3 * 8388608);
    unsigned short* qb  = (unsigned short*)(ws + 50331648);
    unsigned short* kb  = (unsigned short*)(ws + 67108864);
    unsigned short* vt  = (unsigned short*)(ws + 83886080);

    cast_all_kernel<<<12288, 256, 0, stream>>>(x, Wq, Wk, Wv, Wo, xb, wqb);

    gemm_qkv<<<dim3(48, 32), 256, 0, stream>>>(xb, wqb, qb, vt);

    attn_kernel<<<dim3(32, 16), 256, 0, stream>>>(qb, kb, vt, xb);

    gemm_out<<<dim3(16, 32), 256, 0, stream>>>(xb, wob, (float*)d_out);
}